// Round 5
// baseline (374.624 us; speedup 1.0000x reference)
//
#include <hip/hip_runtime.h>

#define DD 160
#define HH 192
#define WW 160
#define VOL (DD * HH * WW)   // 4915200
#define NB 2
#define NC 2

typedef float v2f  __attribute__((ext_vector_type(2)));
typedef float v2fu __attribute__((ext_vector_type(2), aligned(4)));  // 4B-aligned pair load

// 2 consecutive W-voxels per thread. The (x0,x1) corner pair is fetched with a
// single 8B load at xb=clamp(x0,0,W-2); OOB corners carry zero weight so the
// cndmask fix-up value is harmless. 16 pair-gathers/thread instead of 32 dword
// gathers -> ~half the TA/TD segment work.
__global__ __launch_bounds__(256) void warp_kernel(
    const float* __restrict__ x,
    const float* __restrict__ flow,
    float* __restrict__ out)
{
    int t = blockIdx.x * blockDim.x + threadIdx.x;
    int v = t * 2;                       // global voxel index (incl. batch)
    int b = (v >= VOL) ? 1 : 0;
    v -= b * VOL;

    int xw = v % WW;                     // first of 2 x-positions
    int tt = v / WW;
    int yh = tt % HH;
    int zd = tt / HH;

    const float* fb = flow + (size_t)b * 3 * VOL;
    v2f dz2 = __builtin_nontemporal_load((const v2f*)(fb + v));
    v2f dy2 = __builtin_nontemporal_load((const v2f*)(fb + v + VOL));
    v2f dx2 = __builtin_nontemporal_load((const v2f*)(fb + v + 2 * VOL));

    float pz[2] = { zd + dz2.x, zd + dz2.y };
    float py[2] = { yh + dy2.x, yh + dy2.y };
    float px[2] = { xw + dx2.x, (xw + 1) + dx2.y };

    int   rowi[2][4];   // element index of pair base for the 4 (z,y) rows
    float wrow[2][4];   // wz*wy per row (zeroed when that z/y corner is OOB)
    float wx0v[2], wx1v[2];
    bool  psel[2];      // x0 == xb  (interior)

#pragma unroll
    for (int j = 0; j < 2; ++j) {
        float z0f = floorf(pz[j]), y0f = floorf(py[j]), x0f = floorf(px[j]);
        float fz = pz[j] - z0f, fy = py[j] - y0f, fx = px[j] - x0f;
        int z0 = (int)z0f, y0 = (int)y0f, x0 = (int)x0f;
        int z1 = z0 + 1,  y1 = y0 + 1,  x1 = x0 + 1;

        float wz0 = (z0 >= 0 && z0 < DD) ? (1.0f - fz) : 0.0f;
        float wz1 = (z1 >= 0 && z1 < DD) ? fz : 0.0f;
        float wy0 = (y0 >= 0 && y0 < HH) ? (1.0f - fy) : 0.0f;
        float wy1 = (y1 >= 0 && y1 < HH) ? fy : 0.0f;
        wx0v[j] = (x0 >= 0 && x0 < WW) ? (1.0f - fx) : 0.0f;
        wx1v[j] = (x1 >= 0 && x1 < WW) ? fx : 0.0f;

        int z0c = min(max(z0, 0), DD - 1);
        int z1c = min(max(z1, 0), DD - 1);
        int y0c = min(max(y0, 0), HH - 1);
        int y1c = min(max(y1, 0), HH - 1);
        int xb  = min(max(x0, 0), WW - 2);
        psel[j] = (x0 == xb);

        rowi[2 > 0 ? j : j][0] = (z0c * HH + y0c) * WW + xb;  wrow[j][0] = wz0 * wy0;
        rowi[j][1]             = (z0c * HH + y1c) * WW + xb;  wrow[j][1] = wz0 * wy1;
        rowi[j][2]             = (z1c * HH + y0c) * WW + xb;  wrow[j][2] = wz1 * wy0;
        rowi[j][3]             = (z1c * HH + y1c) * WW + xb;  wrow[j][3] = wz1 * wy1;
    }

    const float* xb0 = x + (size_t)b * NC * VOL;
    const float* xb1 = xb0 + VOL;

    float a0[2], a1[2];
#pragma unroll
    for (int j = 0; j < 2; ++j) {
        float s0 = 0.0f, s1 = 0.0f;
        float w0 = wx0v[j], w1 = wx1v[j];
        bool  p  = psel[j];
#pragma unroll
        for (int r = 0; r < 4; ++r) {
            v2fu f0 = *(const v2fu*)(xb0 + rowi[j][r]);
            v2fu f1 = *(const v2fu*)(xb1 + rowi[j][r]);
            // value at x0c / x1c per the p predicate (OOB corner weight is 0)
            float c0_x0 = p ? f0.x : f0.y;
            float c0_x1 = p ? f0.y : f0.x;
            float c1_x0 = p ? f1.x : f1.y;
            float c1_x1 = p ? f1.y : f1.x;
            s0 += wrow[j][r] * (w0 * c0_x0 + w1 * c0_x1);
            s1 += wrow[j][r] * (w0 * c1_x0 + w1 * c1_x1);
        }
        a0[j] = s0;
        a1[j] = s1;
    }

    float* ob = out + (size_t)b * NC * VOL;
    v2f r0; r0.x = a0[0]; r0.y = a0[1];
    v2f r1; r1.x = a1[0]; r1.y = a1[1];
    __builtin_nontemporal_store(r0, (v2f*)(ob + v));
    __builtin_nontemporal_store(r1, (v2f*)(ob + v + VOL));
}

extern "C" void kernel_launch(void* const* d_in, const int* in_sizes, int n_in,
                              void* d_out, int out_size, void* d_ws, size_t ws_size,
                              hipStream_t stream) {
    const float* x    = (const float*)d_in[0];
    const float* flow = (const float*)d_in[1];
    float* out        = (float*)d_out;

    int total_threads = NB * VOL / 2;    // 4,915,200
    int block = 256;
    int grid  = (total_threads + block - 1) / block;  // 19200
    warp_kernel<<<grid, block, 0, stream>>>(x, flow, out);
}